// Round 9
// baseline (1020.316 us; speedup 1.0000x reference)
//
#include <hip/hip_runtime.h>
#include <math.h>

// Problem constants
#define BATCH 32768
#define EMB   2048
#define KDIM  320      // 5*8*8
#define KACT  103      // ceil(0.05*2048)

// GEMM tiling: 1024 threads, BM=16 rows x 2048 cols, 2 cols/thread,
// acc[16][2]=32 VGPRs, 8 waves/SIMD (__launch_bounds__(1024,8)).
// Ledger: r3 BM=8 collapse (latency), r7 wide-B flat, r8 BM=32 collapse
// (occupancy 47%, VALUBusy 56% -> wave count is the binding constraint).
// r9: A via uniform ds_read_b128 from LDS (in-order lgkmcnt -> partial
// waits) replaces the s_load path (out-of-order SMEM -> forced lgkmcnt(0)
// drains, the ~700cy/group serialization implied by r6/r8 busy%).
#define BM 16
#define GTHREADS 1024
#define CIMG 16

// hs row stride in floats: 20 -> 80B rows, 16B-aligned for b128; conv's
// scattered writes land 8-way conflicts (cheap, 80 wave-writes/block).
#define HSS 20

// Radix histogram row stride (16B-aligned, != 0 mod 32 banks)
#define HSTRIDE 260

// ---------------------------------------------------------------------------
// Kernel 0: transpose fc_w (2048 x 320) -> WT (320 x 2048).  (r6 version)
// ---------------------------------------------------------------------------
__global__ __launch_bounds__(256) void transpose_w_kernel(const float* __restrict__ W,
                                                          float* __restrict__ WT) {
  __shared__ float tile[32][33];
  const int k0 = blockIdx.x * 32;
  const int n0 = blockIdx.y * 32;
  const int tx = threadIdx.x;
  const int ty = threadIdx.y;
  for (int i = ty; i < 32; i += 8)
    tile[i][tx] = W[(size_t)(n0 + i) * KDIM + k0 + tx];
  __syncthreads();
  for (int i = ty; i < 32; i += 8)
    WT[(size_t)(k0 + i) * EMB + n0 + tx] = tile[tx][i];
}

// ---------------------------------------------------------------------------
// Fused kernel (r9): conv -> LDS A-tile -> GEMM (A via uniform ds_read_b128,
// B float2 from L2) -> radix-256 select -> binary write.
// No global Ht round-trip, no SMEM in the main loop.
// LDS: xs 49 KB (conv; aliased by 16.6 KB histo in epilogue) + hs 25.6 KB
// (live through loop) = 75.8 KB -> 2 blocks/CU, 8 waves/SIMD.
// z values bit-identical to r6 (same A/B values, same ascending-k order).
// ---------------------------------------------------------------------------
__global__ __launch_bounds__(GTHREADS, 8) void fused_conv_gemm_topk(
    const float* __restrict__ x,
    const float* __restrict__ cw,
    const float* __restrict__ gamma,
    const float* __restrict__ beta,
    const float* __restrict__ mean,
    const float* __restrict__ var,
    const float* __restrict__ WT,
    float* __restrict__ out) {
#pragma clang fp contract(off)
  __shared__ __attribute__((aligned(16))) float smem[12544 + KDIM * HSS];
  __shared__ float wv[45];
  __shared__ float inv_s[5], mu_s[5], be_s[5];
  __shared__ unsigned prefix_s[BM];
  __shared__ unsigned rank_s[BM];

  float* const xs = smem;                      // 16 imgs x 784 (conv phase)
  float* const hs = smem + 12544;              // A-tile: hs[k*20 + m] (live in loop)
  unsigned* const histo = (unsigned*)smem;     // 16.6 KB, aliases dead xs (epilogue)

  const int t    = threadIdx.x;
  const int lane = t & 63;
  const int w    = t >> 6;             // wave 0..15
  const int b0   = blockIdx.x * CIMG;

  // ==== phase 0: stage 16 images ==========================================
  {
    const float4* src = (const float4*)(x + (size_t)b0 * 784);
    float4* dst = (float4*)xs;
    for (int i = t; i < CIMG * 196; i += GTHREADS) dst[i] = src[i];
  }
  if (t < 45) wv[t] = cw[t];
  if (t < 5) {
    inv_s[t] = gamma[t] / sqrtf(var[t] + 1e-5f);  // IEEE div & sqrt
    mu_s[t] = mean[t];
    be_s[t] = beta[t];
  }
  __syncthreads();

  // ==== phase 1: conv+bn+relu+pool, one image per wave -> hs[k][m] ========
  {
    const int img = w;
    const float* xb = xs + img * 784;
    const int py = lane >> 3;
    const int px = lane & 7;

    float xr[5][5];
#pragma unroll
    for (int i = 0; i < 5; ++i)
#pragma unroll
      for (int j = 0; j < 5; ++j)
        xr[i][j] = xb[(3 * py + i) * 28 + 3 * px + j];

#pragma unroll
    for (int c = 0; c < 5; ++c) {
      float wr[9];
#pragma unroll
      for (int i = 0; i < 9; ++i) wr[i] = wv[c * 9 + i];
      const float inv = inv_s[c], mu = mu_s[c], be = be_s[c];
      float mx = -__builtin_huge_valf();
#pragma unroll
      for (int ry = 0; ry < 3; ++ry)
#pragma unroll
        for (int rx = 0; rx < 3; ++rx) {
          float s = 0.0f;
#pragma unroll
          for (int di = 0; di < 3; ++di)
#pragma unroll
            for (int dj = 0; dj < 3; ++dj)
              s = __builtin_fmaf(xr[ry + di][rx + dj], wr[di * 3 + dj], s);
          float t1 = s - mu;
          float t2 = t1 * inv;
          float t3 = t2 + be;
          mx = fmaxf(mx, t3);
        }
      hs[(c * 64 + lane) * HSS + img] = fmaxf(mx, 0.0f);   // k = c*64+lane
    }
  }
  if (t < BM) { prefix_s[t] = 0u; rank_s[t] = KACT; }  // visible after barrier
  __syncthreads();   // hs complete; loop may read

  // ==== phase 2: GEMM main loop (A uniform ds_read_b128, B float2) ========
  const int m0 = blockIdx.x * BM;
  const int nt = t * 2;

  float acc[BM][2];
#pragma unroll
  for (int m = 0; m < BM; ++m) {
    acc[m][0] = 0.0f;
    acc[m][1] = 0.0f;
  }

  const float* wp = WT + nt;

#pragma unroll 4
  for (int k = 0; k < KDIM; ++k) {
    const float* hk = hs + k * HSS;
    // uniform-address LDS reads -> broadcast, conflict-free, in-order lgkmcnt
    const float4 a0 = *(const float4*)(hk + 0);
    const float4 a1 = *(const float4*)(hk + 4);
    const float4 a2 = *(const float4*)(hk + 8);
    const float4 a3 = *(const float4*)(hk + 12);
    const float2 bb = *(const float2*)(wp + (size_t)k * EMB);
    float av[BM];
    av[0]=a0.x; av[1]=a0.y; av[2]=a0.z; av[3]=a0.w;
    av[4]=a1.x; av[5]=a1.y; av[6]=a1.z; av[7]=a1.w;
    av[8]=a2.x; av[9]=a2.y; av[10]=a2.z; av[11]=a2.w;
    av[12]=a3.x; av[13]=a3.y; av[14]=a3.z; av[15]=a3.w;
#pragma unroll
    for (int m = 0; m < BM; ++m) {
      acc[m][0] = __builtin_fmaf(av[m], bb.x, acc[m][0]);
      acc[m][1] = __builtin_fmaf(av[m], bb.y, acc[m][1]);
    }
  }
  __syncthreads();  // xs dead; prefix/rank init visible; histo region free

  // ==== phase 3: radix-256 select of the KACT-th largest per row ==========
  for (int pass = 0; pass < 4; ++pass) {
    const int shift = 24 - pass * 8;
    for (int i = t; i < BM * HSTRIDE; i += GTHREADS) histo[i] = 0u;
    unsigned pref[BM];
#pragma unroll
    for (int m = 0; m < BM; ++m) pref[m] = prefix_s[m];
    __syncthreads();
#pragma unroll
    for (int m = 0; m < BM; ++m) {
#pragma unroll
      for (int j = 0; j < 2; ++j) {
        unsigned u = __float_as_uint(acc[m][j]);
        u = (u & 0x80000000u) ? ~u : (u | 0x80000000u);  // ascending order map
        const bool in = (pass == 0) || ((u >> (shift + 8)) == pref[m]);
        if (in) atomicAdd(&histo[m * HSTRIDE + ((u >> shift) & 255u)], 1u);
      }
    }
    __syncthreads();
    // Scan: wave w handles row w. Lane l covers bins [4l,4l+4); suffix-sum =
    // counts-above. Exactly one lane satisfies the rank bracket.
    {
      const int m = w;
      const unsigned rank = rank_s[m];
      const uint4 c = *(const uint4*)(histo + m * HSTRIDE + lane * 4);
      const unsigned s = c.x + c.y + c.z + c.w;
      unsigned suf = s;
#pragma unroll
      for (int off = 1; off < 64; off <<= 1) {
        const unsigned o = __shfl_down(suf, off);
        if (lane + off < 64) suf += o;
      }
      const unsigned above = suf - s;  // counts in bins > 4*lane+3
      if (above < rank && rank <= suf) {
        unsigned bin, newr;
        if (above + c.w >= rank)                    { bin = lane * 4 + 3; newr = rank - above; }
        else if (above + c.w + c.z >= rank)         { bin = lane * 4 + 2; newr = rank - above - c.w; }
        else if (above + c.w + c.z + c.y >= rank)   { bin = lane * 4 + 1; newr = rank - above - c.w - c.z; }
        else                                        { bin = lane * 4 + 0; newr = rank - above - c.w - c.z - c.y; }
        prefix_s[m] = (prefix_s[m] << 8) | bin;
        rank_s[m] = newr;
      }
    }
    __syncthreads();
  }

  // prefix_s[m] now holds the exact uint-mapped 103rd-largest value
#pragma unroll
  for (int m = 0; m < BM; ++m) {
    const unsigned thr = prefix_s[m];
    float2 o;
#pragma unroll
    for (int j = 0; j < 2; ++j) {
      unsigned u = __float_as_uint(acc[m][j]);
      u = (u & 0x80000000u) ? ~u : (u | 0x80000000u);
      ((float*)&o)[j] = (u >= thr) ? 1.0f : 0.0f;  // tie semantics: z >= topv[:,-1]
    }
    *(float2*)(out + (size_t)(m0 + m) * EMB + nt) = o;
  }
}

// ---------------------------------------------------------------------------
extern "C" void kernel_launch(void* const* d_in, const int* in_sizes, int n_in,
                              void* d_out, int out_size, void* d_ws, size_t ws_size,
                              hipStream_t stream) {
  const float* x      = (const float*)d_in[0];
  const float* conv_w = (const float*)d_in[1];
  const float* gamma  = (const float*)d_in[2];
  const float* beta   = (const float*)d_in[3];
  const float* mean   = (const float*)d_in[4];
  const float* var    = (const float*)d_in[5];
  const float* fc_w   = (const float*)d_in[6];
  float* out = (float*)d_out;

  // workspace: WT (320 x 2048) only -- Ht global round-trip eliminated
  float* WT = (float*)d_ws;

  transpose_w_kernel<<<dim3(KDIM / 32, EMB / 32), dim3(32, 8), 0, stream>>>(fc_w, WT);
  fused_conv_gemm_topk<<<BATCH / CIMG, GTHREADS, 0, stream>>>(
      x, conv_w, gamma, beta, mean, var, WT, out);
}

// Round 11
// 807.823 us; speedup vs baseline: 1.2630x; 1.2630x over previous
//
#include <hip/hip_runtime.h>
#include <math.h>

// Problem constants
#define BATCH 32768
#define EMB   2048
#define KDIM  320      // 5*8*8
#define KACT  103      // ceil(0.05*2048)

// GEMM tiling: 1024 threads, 16 rows x 2048 cols per block, 2 cols/thread.
// acc[16][2]=32 VGPRs, A via uniform s_load (SGPRs), 8 waves/SIMD.
// Loop ledger: r3 BM=8 collapse (latency), r7 wide-B flat/regress, r8 BM=32
// collapse (occupancy), r9 LDS-A collapse (LDS pipe 2-3x oversubscribed:
// 128 ds_read_b128/k/CU vs one LDS unit). r6 structure is the winner; the
// A-path s_load drain is structural (SMEM returns OOO -> lgkmcnt(0) drains
// all, prefetch impossible). r10: attack B-latency OUTLIERS instead -- WT
// gets evicted from L2 by the x/out streams (~33MB/dispatch WT re-fetch in
// r6 FETCH_SIZE) -> nt hints on both streams keep WT resident.
// r10b: nontemporal builtins need native clang vectors (ext_vector_type),
// not HIP_vector_type -- compile fix only, zero semantic change.
#define BM 16
#define GTHREADS 1024
#define CIMG 16

// Radix histogram row stride (16B-aligned, != 0 mod 32 banks)
#define HSTRIDE 260

typedef float floatx4 __attribute__((ext_vector_type(4)));
typedef float floatx2 __attribute__((ext_vector_type(2)));

// ---------------------------------------------------------------------------
// Kernel 0: transpose fc_w (2048 x 320) -> WT (320 x 2048).
// ---------------------------------------------------------------------------
__global__ __launch_bounds__(256) void transpose_w_kernel(const float* __restrict__ W,
                                                          float* __restrict__ WT) {
  __shared__ float tile[32][33];
  const int k0 = blockIdx.x * 32;
  const int n0 = blockIdx.y * 32;
  const int tx = threadIdx.x;
  const int ty = threadIdx.y;
  for (int i = ty; i < 32; i += 8)
    tile[i][tx] = W[(size_t)(n0 + i) * KDIM + k0 + tx];
  __syncthreads();
  for (int i = ty; i < 32; i += 8)
    WT[(size_t)(k0 + i) * EMB + n0 + tx] = tile[tx][i];
}

// ---------------------------------------------------------------------------
// Fused kernel (r10b): r6 structure (verified 600us) + nontemporal hints on
// the two streaming paths (x load, out store). WT and Ht keep normal
// caching (both want L2 residency).
// ---------------------------------------------------------------------------
__global__ __launch_bounds__(GTHREADS, 8) void fused_conv_gemm_topk(
    const float* __restrict__ x,
    const float* __restrict__ cw,
    const float* __restrict__ gamma,
    const float* __restrict__ beta,
    const float* __restrict__ mean,
    const float* __restrict__ var,
    float* __restrict__ HtW,            // A-tile write path
    const float* __restrict__ HtR,      // A-tile read path (same memory, fenced)
    const float* __restrict__ WT,
    float* __restrict__ out) {
#pragma clang fp contract(off)
  __shared__ __attribute__((aligned(16))) float smem[17984];  // xs 12544 | hs 5440
  __shared__ float wv[45];
  __shared__ float inv_s[5], mu_s[5], be_s[5];
  __shared__ unsigned prefix_s[BM];
  __shared__ unsigned rank_s[BM];

  float* const xs = smem;                      // 16 imgs x 784 (conv phase)
  float* const hs = smem + 12544;              // 320 x 17 k-major staging
  unsigned* const histo = (unsigned*)smem;     // BM*HSTRIDE = 16.6 KB (epilogue)

  const int t    = threadIdx.x;
  const int lane = t & 63;
  const int w    = t >> 6;             // wave 0..15
  const int b0   = blockIdx.x * CIMG;

  // ==== phase 0: stage 16 images (nt: x is read exactly once) =============
  {
    const floatx4* src = (const floatx4*)(x + (size_t)b0 * 784);
    floatx4* dst = (floatx4*)xs;
    for (int i = t; i < CIMG * 196; i += GTHREADS)
      dst[i] = __builtin_nontemporal_load(&src[i]);
  }
  if (t < 45) wv[t] = cw[t];
  if (t < 5) {
    inv_s[t] = gamma[t] / sqrtf(var[t] + 1e-5f);  // IEEE div & sqrt
    mu_s[t] = mean[t];
    be_s[t] = beta[t];
  }
  __syncthreads();

  // ==== phase 1: conv+bn+relu+pool, one image per wave ====================
  {
    const int img = w;
    const float* xb = xs + img * 784;
    const int py = lane >> 3;
    const int px = lane & 7;

    float xr[5][5];
#pragma unroll
    for (int i = 0; i < 5; ++i)
#pragma unroll
      for (int j = 0; j < 5; ++j)
        xr[i][j] = xb[(3 * py + i) * 28 + 3 * px + j];

#pragma unroll
    for (int c = 0; c < 5; ++c) {
      float wr[9];
#pragma unroll
      for (int i = 0; i < 9; ++i) wr[i] = wv[c * 9 + i];
      const float inv = inv_s[c], mu = mu_s[c], be = be_s[c];
      float mx = -__builtin_huge_valf();
#pragma unroll
      for (int ry = 0; ry < 3; ++ry)
#pragma unroll
        for (int rx = 0; rx < 3; ++rx) {
          float s = 0.0f;
#pragma unroll
          for (int di = 0; di < 3; ++di)
#pragma unroll
            for (int dj = 0; dj < 3; ++dj)
              s = __builtin_fmaf(xr[ry + di][rx + dj], wr[di * 3 + dj], s);
          float t1 = s - mu;
          float t2 = t1 * inv;
          float t3 = t2 + be;
          mx = fmaxf(mx, t3);
        }
      hs[(c * 64 + lane) * 17 + img] = fmaxf(mx, 0.0f);
    }
  }
  __syncthreads();

  // ==== phase 2: A-tile -> global (normal caching; wants L2) ==============
  {
    float* dst = HtW + (size_t)blockIdx.x * (KDIM * CIMG);
    for (int i = t; i < KDIM * CIMG; i += GTHREADS) {
      const int k = i >> 4;
      const int img = i & 15;
      dst[i] = hs[k * 17 + img];
    }
  }
  if (t < BM) { prefix_s[t] = 0u; rank_s[t] = KACT; }  // visible after barrier
  __syncthreads();   // drains vmcnt -> A-tile visible in L2 for s_loads

  // ==== phase 3: GEMM main loop (bit-identical; LOAD-BEARING, untouched) ==
  const int m0 = blockIdx.x * BM;
  const int nt = t * 2;

  float acc[BM][2];
#pragma unroll
  for (int m = 0; m < BM; ++m) {
    acc[m][0] = 0.0f;
    acc[m][1] = 0.0f;
  }

  const float* Ap = HtR + (size_t)blockIdx.x * (KDIM * BM);  // A(k,m)=Ap[k*16+m]
  const float* wp = WT + nt;

#pragma unroll 4
  for (int k = 0; k < KDIM; ++k) {
    const float* ak = Ap + (size_t)k * BM;
    float av[BM];
#pragma unroll
    for (int m = 0; m < BM; ++m) av[m] = ak[m];   // uniform -> s_load (SGPRs)
    const float2 bb = *(const float2*)(wp + (size_t)k * EMB);
#pragma unroll
    for (int m = 0; m < BM; ++m) {
      acc[m][0] = __builtin_fmaf(av[m], bb.x, acc[m][0]);
      acc[m][1] = __builtin_fmaf(av[m], bb.y, acc[m][1]);
    }
  }
  __syncthreads();  // conv LDS dead; prefix/rank init visible; histo free

  // ==== phase 4: radix-256 select of the KACT-th largest per row ==========
  for (int pass = 0; pass < 4; ++pass) {
    const int shift = 24 - pass * 8;
    for (int i = t; i < BM * HSTRIDE; i += GTHREADS) histo[i] = 0u;
    unsigned pref[BM];
#pragma unroll
    for (int m = 0; m < BM; ++m) pref[m] = prefix_s[m];
    __syncthreads();
#pragma unroll
    for (int m = 0; m < BM; ++m) {
#pragma unroll
      for (int j = 0; j < 2; ++j) {
        unsigned u = __float_as_uint(acc[m][j]);
        u = (u & 0x80000000u) ? ~u : (u | 0x80000000u);  // ascending order map
        const bool in = (pass == 0) || ((u >> (shift + 8)) == pref[m]);
        if (in) atomicAdd(&histo[m * HSTRIDE + ((u >> shift) & 255u)], 1u);
      }
    }
    __syncthreads();
    // Scan: wave w handles row w. Lane l covers bins [4l,4l+4); suffix-sum =
    // counts-above. Exactly one lane satisfies the rank bracket.
    {
      const int m = w;
      const unsigned rank = rank_s[m];
      const uint4 c = *(const uint4*)(histo + m * HSTRIDE + lane * 4);
      const unsigned s = c.x + c.y + c.z + c.w;
      unsigned suf = s;
#pragma unroll
      for (int off = 1; off < 64; off <<= 1) {
        const unsigned o = __shfl_down(suf, off);
        if (lane + off < 64) suf += o;
      }
      const unsigned above = suf - s;  // counts in bins > 4*lane+3
      if (above < rank && rank <= suf) {
        unsigned bin, newr;
        if (above + c.w >= rank)                    { bin = lane * 4 + 3; newr = rank - above; }
        else if (above + c.w + c.z >= rank)         { bin = lane * 4 + 2; newr = rank - above - c.w; }
        else if (above + c.w + c.z + c.y >= rank)   { bin = lane * 4 + 1; newr = rank - above - c.w - c.z; }
        else                                        { bin = lane * 4 + 0; newr = rank - above - c.w - c.z - c.y; }
        prefix_s[m] = (prefix_s[m] << 8) | bin;
        rank_s[m] = newr;
      }
    }
    __syncthreads();
  }

  // prefix_s[m] now holds the exact uint-mapped 103rd-largest value
#pragma unroll
  for (int m = 0; m < BM; ++m) {
    const unsigned thr = prefix_s[m];
    floatx2 o;
#pragma unroll
    for (int j = 0; j < 2; ++j) {
      unsigned u = __float_as_uint(acc[m][j]);
      u = (u & 0x80000000u) ? ~u : (u | 0x80000000u);
      o[j] = (u >= thr) ? 1.0f : 0.0f;  // tie semantics: z >= topv[:,-1]
    }
    __builtin_nontemporal_store(o, (floatx2*)(out + (size_t)(m0 + m) * EMB + nt));
  }
}

// ---------------------------------------------------------------------------
extern "C" void kernel_launch(void* const* d_in, const int* in_sizes, int n_in,
                              void* d_out, int out_size, void* d_ws, size_t ws_size,
                              hipStream_t stream) {
  const float* x      = (const float*)d_in[0];
  const float* conv_w = (const float*)d_in[1];
  const float* gamma  = (const float*)d_in[2];
  const float* beta   = (const float*)d_in[3];
  const float* mean   = (const float*)d_in[4];
  const float* var    = (const float*)d_in[5];
  const float* fc_w   = (const float*)d_in[6];
  float* out = (float*)d_out;

  // workspace: Ht tile-major (2048 tiles x 320 x 16 f32 = 40 MB) | WT (320x2048)
  float* Ht = (float*)d_ws;
  float* WT = (float*)d_ws + (size_t)KDIM * BATCH;

  transpose_w_kernel<<<dim3(KDIM / 32, EMB / 32), dim3(32, 8), 0, stream>>>(fc_w, WT);
  fused_conv_gemm_topk<<<BATCH / CIMG, GTHREADS, 0, stream>>>(
      x, conv_w, gamma, beta, mean, var, Ht, Ht, WT, out);
}